// Round 6
// baseline (730.503 us; speedup 1.0000x reference)
//
#include <hip/hip_runtime.h>

#define EPS 1e-5f
#define WAVES 4

typedef __attribute__((ext_vector_type(8)))  short short8;
typedef __attribute__((ext_vector_type(4)))  short short4_t;
typedef __attribute__((ext_vector_type(16))) float f32x16;
typedef __attribute__((ext_vector_type(4)))  float f32x4;

__device__ inline unsigned f2bf(float f) {
    unsigned u = __builtin_bit_cast(unsigned, f);
    return (u + 0x7fffu + ((u >> 16) & 1u)) >> 16;   // RNE f32->bf16
}

// prep: two regions of d_ws
//  [0)      w2f:  bf16 w2 in mfma_f32_32x32x16_bf16 B-frag order
//           w2f[((nf*16+ks)*64+lane)*8+e] = bf16(w2[ks*16+(lane>>5)*8+e][nf*32+(lane&31)])
//  [131072) emb2: emb + b2 broadcast (folds b2 out of the epilogue)
__global__ void prep(const float* __restrict__ w2, const float* __restrict__ emb,
                     const float* __restrict__ b2,
                     unsigned short* __restrict__ w2f, float* __restrict__ emb2) {
    int idx = blockIdx.x * 256 + threadIdx.x;
    if (idx < 65536) {
        int e    = idx & 7;
        int lane = (idx >> 3) & 63;
        int ks   = (idx >> 9) & 15;
        int nf   = idx >> 13;
        int k    = ks * 16 + ((lane >> 5) << 3) + e;
        int n    = nf * 32 + (lane & 31);
        w2f[idx] = (unsigned short)f2bf(w2[k * 256 + n]);
    } else if (idx < 65536 + 25600) {
        int i = idx - 65536;
        emb2[i] = emb[i] + b2[i & 255];
    }
}

__global__ __launch_bounds__(256, 2) void fused_kernel(
    const int* __restrict__ z, const float* __restrict__ x,
    const float* __restrict__ w1, const float* __restrict__ b1,
    const unsigned short* __restrict__ w2f, const float* __restrict__ emb2,
    const float* __restrict__ gamma, const float* __restrict__ beta,
    float* __restrict__ out, int N)
{
    // All LDS PER-WAVE: no __syncthreads (within-wave producer/consumer; DS pipe
    // is in-order per wave). Persistent waves: ~8 tiles each, so tile t+1's
    // gather+silu overlaps tile t's NT-store drain (shared vmcnt).
    __shared__ char  p_lds[WAVES * 16384];   // per-wave 32x256 bf16 A-tile (swizzled)
    __shared__ float x_lds[WAVES][32][4];
    __shared__ int   z_lds[WAVES][32];

    const int tid  = threadIdx.x;
    const int wave = tid >> 6;
    const int lane = tid & 63;
    const int l31  = lane & 31;
    const int h    = lane >> 5;
    char* pbuf = p_lds + wave * 16384;

    // hoisted once per wave lifetime (amortized over ~8 tiles):
    const int  c0  = lane * 4;
    const f32x4 w1a = *(const f32x4*)(w1 + c0);
    const f32x4 w1b = *(const f32x4*)(w1 + 256 + c0);
    const f32x4 w1c = *(const f32x4*)(w1 + 512 + c0);
    const f32x4 b1v = *(const f32x4*)(b1 + c0);
    float gv[8], bv[8];
#pragma unroll
    for (int nf = 0; nf < 8; ++nf) {
        int c = nf * 32 + l31;
        gv[nf] = gamma[c]; bv[nf] = beta[c];
    }

    const int tiles  = N >> 5;
    const int stride = gridDim.x * WAVES;
    int t = blockIdx.x * WAVES + wave;
    if (t >= tiles) return;                  // per-wave exit legal: no barriers

    // prefetch tile-0 z/x into registers
    float px0 = 0.f, px1 = 0.f, px2 = 0.f; int pz = 0;
    if (lane < 32) {
        int r = (t << 5) + lane;
        px0 = x[r * 3 + 0]; px1 = x[r * 3 + 1]; px2 = x[r * 3 + 2];
        pz  = z[r];
    }

    for (; t < tiles; t += stride) {
        const int R = t << 5;

        // stage prefetched z/x (same-wave DS ordering, no barrier)
        if (lane < 32) {
            x_lds[wave][lane][0] = px0;
            x_lds[wave][lane][1] = px1;
            x_lds[wave][lane][2] = px2;
            z_lds[wave][lane]    = pz;
        }

        // ---- init acc with emb2 gather (C/D layout): 128 L2-hit loads fly
        // while the silu chain below executes.
        f32x16 acc[8];
#pragma unroll
        for (int j = 0; j < 16; ++j) {
            const int rl = (j & 3) + ((j >> 2) << 3) + (h << 2);
            const float* er = emb2 + (size_t)z_lds[wave][rl] * 256 + l31;
#pragma unroll
            for (int nf = 0; nf < 8; ++nf)
                acc[nf][j] = er[nf * 32];
        }

        // p = silu(x @ w1 + b1) -> bf16 LDS tile, XOR-swizzled rows
#pragma unroll
        for (int r = 0; r < 32; ++r) {
            float x0 = x_lds[wave][r][0];
            float x1 = x_lds[wave][r][1];
            float x2 = x_lds[wave][r][2];
            short4_t pv;
#pragma unroll
            for (int j = 0; j < 4; ++j) {
                float tv = x0 * w1a[j] + x1 * w1b[j] + x2 * w1c[j] + b1v[j];
                float s  = tv * __builtin_amdgcn_rcpf(1.f + __expf(-tv));
                pv[j] = (short)f2bf(s);
            }
            int off = (r * 512 + lane * 8) ^ ((r & 7) << 4);
            *(short4_t*)(pbuf + off) = pv;
        }

        // GEMM: [32,256] @ [256,256] via mfma_f32_32x32x16_bf16 (acc has emb2)
#pragma unroll
        for (int ks = 0; ks < 16; ++ks) {
            int aoff = (l31 * 512 + ks * 32 + h * 16) ^ ((l31 & 7) << 4);
            short8 a = *(const short8*)(pbuf + aoff);
            const unsigned short* bp = w2f + ks * 512 + lane * 8;
#pragma unroll
            for (int nf = 0; nf < 8; ++nf) {
                short8 b = *(const short8*)(bp + nf * 8192);
                acc[nf] = __builtin_amdgcn_mfma_f32_32x32x16_bf16(a, b, acc[nf], 0, 0, 0);
            }
        }

        // prefetch next tile's z/x BEFORE the epilogue so the loads drain
        // under the LN+store phase
        {
            int tn = t + stride;
            if (tn < tiles && lane < 32) {
                int r = (tn << 5) + lane;
                px0 = x[r * 3 + 0]; px1 = x[r * 3 + 1]; px2 = x[r * 3 + 2];
                pz  = z[r];
            }
        }

        // epilogue: LayerNorm (row in one lane-half) ; NT stores (bypass L2
        // write-allocate RFO). Stores drain under next tile's gather+silu.
#pragma unroll
        for (int j = 0; j < 16; ++j) {
            const int rl = (j & 3) + ((j >> 2) << 3) + (h << 2);
            float hv[8];
            float hsum = 0.f, hsq = 0.f;
#pragma unroll
            for (int nf = 0; nf < 8; ++nf) {
                float v = acc[nf][j];
                hv[nf] = v; hsum += v; hsq += v * v;
            }
#pragma unroll
            for (int d = 1; d < 32; d <<= 1) {
                hsum += __shfl_xor(hsum, d, 64);
                hsq  += __shfl_xor(hsq,  d, 64);
            }
            float mu  = hsum * (1.f / 256.f);
            float var = hsq * (1.f / 256.f) - mu * mu;
            float rs  = rsqrtf(var + EPS);
            float* orow = out + (size_t)(R + rl) * 256 + l31;
#pragma unroll
            for (int nf = 0; nf < 8; ++nf)
                __builtin_nontemporal_store((hv[nf] - mu) * rs * gv[nf] + bv[nf],
                                            orow + nf * 32);
        }
    }
}

extern "C" void kernel_launch(void* const* d_in, const int* in_sizes, int n_in,
                              void* d_out, int out_size, void* d_ws, size_t ws_size,
                              hipStream_t stream) {
    const int*   z     = (const int*)d_in[0];
    const float* x     = (const float*)d_in[1];
    const float* emb   = (const float*)d_in[2];
    const float* w1    = (const float*)d_in[3];
    const float* b1    = (const float*)d_in[4];
    const float* w2    = (const float*)d_in[5];
    const float* b2    = (const float*)d_in[6];
    const float* gamma = (const float*)d_in[7];
    const float* beta  = (const float*)d_in[8];
    float* out = (float*)d_out;
    const int N = in_sizes[0];

    unsigned short* w2f  = (unsigned short*)d_ws;              // 128 KB
    float*          emb2 = (float*)((char*)d_ws + 131072);     // 100 KB

    prep<<<(65536 + 25600 + 255) / 256, 256, 0, stream>>>(w2, emb, b2, w2f, emb2);

    int tiles  = N >> 5;
    int blocks = 512;                        // 2/CU resident -> fully persistent
    int maxb   = (tiles + WAVES - 1) / WAVES;
    if (blocks > maxb) blocks = maxb;
    fused_kernel<<<blocks, 256, 0, stream>>>(z, x, w1, b1, w2f, emb2,
                                             gamma, beta, out, N);
}

// Round 7
// 184.997 us; speedup vs baseline: 3.9487x; 3.9487x over previous
//
#include <hip/hip_runtime.h>

#define EPS 1e-5f
#define WAVES 4

typedef __attribute__((ext_vector_type(8)))  short short8;
typedef __attribute__((ext_vector_type(4)))  short short4_t;
typedef __attribute__((ext_vector_type(16))) float f32x16;
typedef __attribute__((ext_vector_type(4)))  float f32x4;

__device__ inline unsigned f2bf(float f) {
    unsigned u = __builtin_bit_cast(unsigned, f);
    return (u + 0x7fffu + ((u >> 16) & 1u)) >> 16;   // RNE f32->bf16
}

// prep: two regions of d_ws
//  [0)      w2f:  bf16 w2 in mfma_f32_32x32x16_bf16 B-frag order
//           w2f[((nf*16+ks)*64+lane)*8+e] = bf16(w2[ks*16+(lane>>5)*8+e][nf*32+(lane&31)])
//  [131072) embp: (emb + b2) as bf16 PAIRS, column-interleaved so one u32 load
//           per lane yields its cols for nf=2g and nf=2g+1:
//           embp[row*128 + g*32 + c] = pack(bf16(e[row][g*64+c]), bf16(e[row][g*64+32+c]))
__global__ void prep(const float* __restrict__ w2, const float* __restrict__ emb,
                     const float* __restrict__ b2,
                     unsigned short* __restrict__ w2f, unsigned* __restrict__ embp) {
    int idx = blockIdx.x * 256 + threadIdx.x;
    if (idx < 65536) {
        int e    = idx & 7;
        int lane = (idx >> 3) & 63;
        int ks   = (idx >> 9) & 15;
        int nf   = idx >> 13;
        int k    = ks * 16 + ((lane >> 5) << 3) + e;
        int n    = nf * 32 + (lane & 31);
        w2f[idx] = (unsigned short)f2bf(w2[k * 256 + n]);
    } else if (idx < 65536 + 12800) {
        int i   = idx - 65536;
        int row = i >> 7;
        int w   = i & 127;
        int g   = w >> 5;
        int c   = w & 31;
        int clo = g * 64 + c;
        int chi = clo + 32;
        unsigned lo = f2bf(emb[row * 256 + clo] + b2[clo]);
        unsigned hi = f2bf(emb[row * 256 + chi] + b2[chi]);
        embp[i] = lo | (hi << 16);
    }
}

__global__ __launch_bounds__(256, 2) void fused_kernel(
    const int* __restrict__ z, const float* __restrict__ x,
    const float* __restrict__ w1, const float* __restrict__ b1,
    const unsigned short* __restrict__ w2f, const unsigned* __restrict__ embp,
    const float* __restrict__ gamma, const float* __restrict__ beta,
    float* __restrict__ out, int N)
{
    // All LDS PER-WAVE: no __syncthreads (within-wave producer/consumer; DS pipe
    // is in-order per wave). One-shot: one 32-row tile per wave (R4 structure —
    // persistence and 16-row tiles both measured slower).
    __shared__ char  p_lds[WAVES * 16384];   // per-wave 32x256 bf16 A-tile (swizzled)
    __shared__ float x_lds[WAVES][32][4];
    __shared__ int   z_lds[WAVES][32];

    const int tid  = threadIdx.x;
    const int wave = tid >> 6;
    const int lane = tid & 63;
    const int l31  = lane & 31;
    const int h    = lane >> 5;
    char* pbuf = p_lds + wave * 16384;

    const int tiles = N >> 5;
    const int t = blockIdx.x * WAVES + wave;
    if (t >= tiles) return;                  // per-wave exit legal: no barriers
    const int R = t << 5;

    if (lane < 32) {
        int r = R + lane;
        x_lds[wave][lane][0] = x[r * 3 + 0];
        x_lds[wave][lane][1] = x[r * 3 + 1];
        x_lds[wave][lane][2] = x[r * 3 + 2];
        z_lds[wave][lane]    = z[r];
    }

    // ---- init acc with packed-bf16 emb2 gather (C/D layout): 64 u32 loads
    // (half of f32) fly while the silu chain below executes.
    f32x16 acc[8];
#pragma unroll
    for (int j = 0; j < 16; ++j) {
        const int rl = (j & 3) + ((j >> 2) << 3) + (h << 2);
        const unsigned* er = embp + z_lds[wave][rl] * 128 + l31;
#pragma unroll
        for (int g = 0; g < 4; ++g) {
            unsigned u = er[g * 32];
            acc[2 * g][j]     = __builtin_bit_cast(float, u << 16);
            acc[2 * g + 1][j] = __builtin_bit_cast(float, u & 0xffff0000u);
        }
    }

    // hoisted per-lane weights: this lane computes p columns [lane*4, lane*4+3]
    const int  c0  = lane * 4;
    const f32x4 w1a = *(const f32x4*)(w1 + c0);
    const f32x4 w1b = *(const f32x4*)(w1 + 256 + c0);
    const f32x4 w1c = *(const f32x4*)(w1 + 512 + c0);
    const f32x4 b1v = *(const f32x4*)(b1 + c0);
    float gv[8], bv[8];
#pragma unroll
    for (int nf = 0; nf < 8; ++nf) {
        int c = nf * 32 + l31;
        gv[nf] = gamma[c]; bv[nf] = beta[c];
    }

    // p = silu(x @ w1 + b1) -> bf16 LDS tile, XOR-swizzled rows
#pragma unroll
    for (int r = 0; r < 32; ++r) {
        float x0 = x_lds[wave][r][0];
        float x1 = x_lds[wave][r][1];
        float x2 = x_lds[wave][r][2];
        short4_t pv;
#pragma unroll
        for (int j = 0; j < 4; ++j) {
            float tv = x0 * w1a[j] + x1 * w1b[j] + x2 * w1c[j] + b1v[j];
            float s  = tv * __builtin_amdgcn_rcpf(1.f + __expf(-tv));
            pv[j] = (short)f2bf(s);
        }
        int off = (r * 512 + lane * 8) ^ ((r & 7) << 4);
        *(short4_t*)(pbuf + off) = pv;
    }

    // GEMM: [32,256] @ [256,256] via mfma_f32_32x32x16_bf16 (acc has emb2)
#pragma unroll
    for (int ks = 0; ks < 16; ++ks) {
        int aoff = (l31 * 512 + ks * 32 + h * 16) ^ ((l31 & 7) << 4);
        short8 a = *(const short8*)(pbuf + aoff);
        const unsigned short* bp = w2f + ks * 512 + lane * 8;
#pragma unroll
        for (int nf = 0; nf < 8; ++nf) {
            short8 b = *(const short8*)(bp + nf * 8192);
            acc[nf] = __builtin_amdgcn_mfma_f32_32x32x16_bf16(a, b, acc[nf], 0, 0, 0);
        }
    }

    // epilogue: LayerNorm (row in one lane-half) ; NT stores (bypass L2
    // write-allocate RFO).
#pragma unroll
    for (int j = 0; j < 16; ++j) {
        const int rl = (j & 3) + ((j >> 2) << 3) + (h << 2);
        float hv[8];
        float hsum = 0.f, hsq = 0.f;
#pragma unroll
        for (int nf = 0; nf < 8; ++nf) {
            float v = acc[nf][j];
            hv[nf] = v; hsum += v; hsq += v * v;
        }
#pragma unroll
        for (int d = 1; d < 32; d <<= 1) {
            hsum += __shfl_xor(hsum, d, 64);
            hsq  += __shfl_xor(hsq,  d, 64);
        }
        float mu  = hsum * (1.f / 256.f);
        float var = hsq * (1.f / 256.f) - mu * mu;
        float rs  = rsqrtf(var + EPS);
        float* orow = out + (size_t)(R + rl) * 256 + l31;
#pragma unroll
        for (int nf = 0; nf < 8; ++nf)
            __builtin_nontemporal_store((hv[nf] - mu) * rs * gv[nf] + bv[nf],
                                        orow + nf * 32);
    }
}

extern "C" void kernel_launch(void* const* d_in, const int* in_sizes, int n_in,
                              void* d_out, int out_size, void* d_ws, size_t ws_size,
                              hipStream_t stream) {
    const int*   z     = (const int*)d_in[0];
    const float* x     = (const float*)d_in[1];
    const float* emb   = (const float*)d_in[2];
    const float* w1    = (const float*)d_in[3];
    const float* b1    = (const float*)d_in[4];
    const float* w2    = (const float*)d_in[5];
    const float* b2    = (const float*)d_in[6];
    const float* gamma = (const float*)d_in[7];
    const float* beta  = (const float*)d_in[8];
    float* out = (float*)d_out;
    const int N = in_sizes[0];

    unsigned short* w2f  = (unsigned short*)d_ws;              // 128 KB
    unsigned*       embp = (unsigned*)((char*)d_ws + 131072);  // 50 KB bf16-pair emb+b2

    prep<<<(65536 + 12800 + 255) / 256, 256, 0, stream>>>(w2, emb, b2, w2f, embp);

    int tiles  = N >> 5;
    int blocks = (tiles + WAVES - 1) / WAVES;  // one tile per wave, one-shot
    fused_kernel<<<blocks, 256, 0, stream>>>(z, x, w1, b1, w2f, embp,
                                             gamma, beta, out, N);
}